// Round 12
// baseline (131977.319 us; speedup 1.0000x reference)
//
#include <hip/hip_runtime.h>
#include <math.h>

// ---------------------------------------------------------------------------
// 2-layer LSTM, batch=1, T=32768, I=128, H=512  (PyTorch gate order i,f,g,o)
//
// 24 persistent WGs x 512 threads (grid == 24).
//   WG 0..15  : layer-1, WG k owns h1[k*32 .. k*32+32)
//   WG 16..23 : layer-2, WG j owns h2[(j-16)*16 ..+16), runs 1 step behind.
//
// ROUND-12 RESTRUCTURE (protocol constants proven in r2-r11):
//  - (tag<<32)|f32bits u64 words, depth-8 rings, device-scope sc1 only
//    (r6/r7 proved the sc0 "fast ring" never delivers cross-XCD; dropping it
//    removes ~4 wasted sc0 RTs of detection lag per step).
//  - PER-THREAD DIRECT CONSUMPTION: each thread polls its own 16-pair ring
//    slice (one 8x dwordx4 asm block, single vmcnt). The poll IS the operand
//    load; a lane FMAs its slice the moment its tags match (divergent), so
//    arrived lanes' compute overlaps stragglers' polling. No LDS staging,
//    no barrier before compute.
//  - Publish h immediately after reduce+activation; __syncthreads + progress
//    tag AFTER publish -> barrier is off the inter-WG critical path.
//  - Overwrite guard (tags >= n-3) in wave 3 every 4th step (off-path).
// ---------------------------------------------------------------------------

#define T_STEPS 32768
#define L1WG    16
#define NWG     24
#define BLK     512
#define RD      8

// ws u32 layout
#define ABT_OFF  9
#define TAG_OFF  32                      // tags[24]
#define H1_OFF   1024                    // u64[RD][512] -> 8192 u32
#define H2_OFF   (H1_OFF + RD * 512 * 2) // u64[RD][128] -> 2048 u32
#define WS_WORDS (H2_OFF + RD * 128 * 2) // 11264 u32 = 45 KB

typedef unsigned int uint4v __attribute__((ext_vector_type(4)));

__device__ __forceinline__ float sigm(float x) { return 1.0f / (1.0f + __expf(-x)); }
__device__ __forceinline__ float tanh_fast(float x) { return 1.0f - 2.0f / (__expf(2.0f * x) + 1.0f); }

// ---- device-scope (sc1) access helpers -----------------------------------
__device__ __forceinline__ unsigned ld_u32_sc1(const unsigned* p) {
    unsigned r;
    asm volatile("global_load_dword %0, %1, off sc1\n\ts_waitcnt vmcnt(0)"
                 : "=v"(r) : "v"(p) : "memory");
    return r;
}
__device__ __forceinline__ void st_u32_sc1(unsigned* p, unsigned v) {
    asm volatile("global_store_dword %0, %1, off sc1" :: "v"(p), "v"(v) : "memory");
}
__device__ __forceinline__ void st_u64_sc1(unsigned long long* p, unsigned long long v) {
    asm volatile("global_store_dwordx2 %0, %1, off sc1" :: "v"(p), "v"(v) : "memory");
}
__device__ __forceinline__ void ld2x16_sc1(const unsigned long long* p, uint4v& A, uint4v& B) {
    asm volatile("global_load_dwordx4 %0, %2, off sc1\n\t"
                 "global_load_dwordx4 %1, %3, off sc1\n\t"
                 "s_waitcnt vmcnt(0)"
                 : "=&v"(A), "=&v"(B) : "v"(p), "v"(p + 2) : "memory");
}
// 8 x dwordx4 (16 ring pairs), one round trip, waitcnt inside the block
__device__ __forceinline__ void ld8x16_sc1(const unsigned long long* p,
    uint4v& A0, uint4v& A1, uint4v& A2, uint4v& A3,
    uint4v& A4, uint4v& A5, uint4v& A6, uint4v& A7)
{
    asm volatile(
        "global_load_dwordx4 %0, %8, off sc1\n\t"
        "global_load_dwordx4 %1, %9, off sc1\n\t"
        "global_load_dwordx4 %2, %10, off sc1\n\t"
        "global_load_dwordx4 %3, %11, off sc1\n\t"
        "global_load_dwordx4 %4, %12, off sc1\n\t"
        "global_load_dwordx4 %5, %13, off sc1\n\t"
        "global_load_dwordx4 %6, %14, off sc1\n\t"
        "global_load_dwordx4 %7, %15, off sc1\n\t"
        "s_waitcnt vmcnt(0)"
        : "=&v"(A0), "=&v"(A1), "=&v"(A2), "=&v"(A3),
          "=&v"(A4), "=&v"(A5), "=&v"(A6), "=&v"(A7)
        : "v"(p), "v"(p + 2), "v"(p + 4), "v"(p + 6),
          "v"(p + 8), "v"(p + 10), "v"(p + 12), "v"(p + 14)
        : "memory");
}

__global__ void lstm_init(unsigned int* ws)
{
    int i = blockIdx.x * blockDim.x + threadIdx.x;
    if (i < WS_WORDS) ws[i] = 0u;
}

__global__ __launch_bounds__(BLK, 2) void lstm_persist(
    const float* __restrict__ x,      // [32768][128]
    const float* __restrict__ Wih1,   // [2048][128]
    const float* __restrict__ Whh1,   // [2048][512]
    const float* __restrict__ bih1,
    const float* __restrict__ bhh1,
    const float* __restrict__ Wih2,   // [512][512]
    const float* __restrict__ Whh2,   // [512][128]
    const float* __restrict__ bih2,
    const float* __restrict__ bhh2,
    float* __restrict__ out,          // [32768][128]
    unsigned int* ws)
{
    const int role = blockIdx.x;      // 0..23
    const int tid  = threadIdx.x;
    const int wave = tid >> 6;
    const int lane = tid & 63;
    const int ct   = tid & 31;        // col-tile: 16 prim cols + 4 sec cols
    const int rt   = tid >> 5;        // 0..15

    __shared__ unsigned s_ab[1];

    unsigned* abf  = ws + ABT_OFF;
    unsigned* tags = ws + TAG_OFF;
    unsigned long long* h1r = (unsigned long long*)(ws + H1_OFF);
    unsigned long long* h2r = (unsigned long long*)(ws + H2_OFF);

    if (tid == 0) s_ab[0] = 0u;

    const bool isL1 = role < L1WG;

    if (isL1) {
        // ========== LAYER 1: 32 h/WG; thread = 2 h x 4 gates x 20 cols =====
        const int hb = role * 32;

        float wA[2][4][16], wB[2][4][4], bia[2][4];
#pragma unroll
        for (int hh = 0; hh < 2; ++hh) {
#pragma unroll
            for (int q = 0; q < 4; ++q) {
                const int grow = q * 512 + hb + hh * 16 + rt;
                const float4* pa = (const float4*)(Whh1 + (size_t)grow * 512 + ct * 16);
#pragma unroll
                for (int c = 0; c < 4; ++c) {
                    float4 f = pa[c];
                    wA[hh][q][c * 4 + 0] = f.x; wA[hh][q][c * 4 + 1] = f.y;
                    wA[hh][q][c * 4 + 2] = f.z; wA[hh][q][c * 4 + 3] = f.w;
                }
                float4 fb = *(const float4*)(Wih1 + (size_t)grow * 128 + ct * 4);
                wB[hh][q][0] = fb.x; wB[hh][q][1] = fb.y;
                wB[hh][q][2] = fb.z; wB[hh][q][3] = fb.w;
                bia[hh][q] = bih1[grow] + bhh1[grow];
            }
        }

        float cst0 = 0.0f, cst1 = 0.0f;
        float4 vx = *(const float4*)(x + ct * 4);   // x[0]
        __syncthreads();   // s_ab visible

        for (int n = 0; n < T_STEPS; ++n) {
            // ---- wave 3: overwrite guard, every 4th step -----------------
            if (wave == 3 && n >= 8 && (n & 3) == 0 && lane < NWG) {
                const int thr = n - 3;
                unsigned sp = 0;
                for (;;) {
                    int ok = ((int)ld_u32_sc1(&tags[lane]) >= thr);
                    if (__all(ok)) break;
                    if ((++sp & 255u) == 0u) {
                        if (ld_u32_sc1(abf) != 0u) { s_ab[0] = 1u; break; }
                        if (sp >= (1u << 20)) { st_u32_sc1(abf, 1u); s_ab[0] = 1u; break; }
                    }
                }
            }

            // ---- direct poll + FMA-on-arrival ----------------------------
            float a00 = 0.f, a01 = 0.f, a02 = 0.f, a03 = 0.f;
            float a10 = 0.f, a11 = 0.f, a12 = 0.f, a13 = 0.f;
            {
                const unsigned e = (unsigned)n;
                const unsigned long long* p =
                    h1r + (size_t)((n - 1) & (RD - 1)) * 512 + ct * 16;
                bool done = false;
                unsigned sp = 0;
                for (;;) {
                    if (!done) {
                        uint4v A0, A1, A2, A3, A4, A5, A6, A7;
                        ld8x16_sc1(p, A0, A1, A2, A3, A4, A5, A6, A7);
                        int ok = (A0.y == e) & (A0.w == e) & (A1.y == e) & (A1.w == e)
                               & (A2.y == e) & (A2.w == e) & (A3.y == e) & (A3.w == e)
                               & (A4.y == e) & (A4.w == e) & (A5.y == e) & (A5.w == e)
                               & (A6.y == e) & (A6.w == e) & (A7.y == e) & (A7.w == e);
                        if (ok) {
                            uint4v W[8] = { A0, A1, A2, A3, A4, A5, A6, A7 };
#pragma unroll
                            for (int k = 0; k < 8; ++k) {
                                const float v0 = __uint_as_float(W[k].x);
                                const float v1 = __uint_as_float(W[k].z);
                                a00 = fmaf(wA[0][0][2*k], v0, fmaf(wA[0][0][2*k+1], v1, a00));
                                a01 = fmaf(wA[0][1][2*k], v0, fmaf(wA[0][1][2*k+1], v1, a01));
                                a02 = fmaf(wA[0][2][2*k], v0, fmaf(wA[0][2][2*k+1], v1, a02));
                                a03 = fmaf(wA[0][3][2*k], v0, fmaf(wA[0][3][2*k+1], v1, a03));
                                a10 = fmaf(wA[1][0][2*k], v0, fmaf(wA[1][0][2*k+1], v1, a10));
                                a11 = fmaf(wA[1][1][2*k], v0, fmaf(wA[1][1][2*k+1], v1, a11));
                                a12 = fmaf(wA[1][2][2*k], v0, fmaf(wA[1][2][2*k+1], v1, a12));
                                a13 = fmaf(wA[1][3][2*k], v0, fmaf(wA[1][3][2*k+1], v1, a13));
                            }
                            const float sx[4] = { vx.x, vx.y, vx.z, vx.w };
#pragma unroll
                            for (int j = 0; j < 4; ++j) {
                                a00 = fmaf(wB[0][0][j], sx[j], a00);
                                a01 = fmaf(wB[0][1][j], sx[j], a01);
                                a02 = fmaf(wB[0][2][j], sx[j], a02);
                                a03 = fmaf(wB[0][3][j], sx[j], a03);
                                a10 = fmaf(wB[1][0][j], sx[j], a10);
                                a11 = fmaf(wB[1][1][j], sx[j], a11);
                                a12 = fmaf(wB[1][2][j], sx[j], a12);
                                a13 = fmaf(wB[1][3][j], sx[j], a13);
                            }
                            done = true;
                        }
                    }
                    if (__all(done)) break;
                    if ((++sp & 63u) == 0u) {
                        if (ld_u32_sc1(abf) != 0u) { s_ab[0] = 1u; break; }
                        if (sp >= (1u << 20)) { st_u32_sc1(abf, 1u); s_ab[0] = 1u; break; }
                    }
                }
            }

            // prefetch next x row (off critical path)
            {
                const int tn = (n + 1 < T_STEPS) ? (n + 1) : (T_STEPS - 1);
                vx = *(const float4*)(x + (size_t)tn * 128 + ct * 4);
            }

            // ---- reduce over 32 ct lanes ---------------------------------
#pragma unroll
            for (int m = 16; m >= 1; m >>= 1) {
                a00 += __shfl_xor(a00, m, 64); a01 += __shfl_xor(a01, m, 64);
                a02 += __shfl_xor(a02, m, 64); a03 += __shfl_xor(a03, m, 64);
                a10 += __shfl_xor(a10, m, 64); a11 += __shfl_xor(a11, m, 64);
                a12 += __shfl_xor(a12, m, 64); a13 += __shfl_xor(a13, m, 64);
            }

            // ---- activations (identical across ct lanes) + publish -------
            {
                const float i0 = sigm(a00 + bia[0][0]);
                const float f0 = sigm(a01 + bia[0][1]);
                const float g0 = tanh_fast(a02 + bia[0][2]);
                const float o0 = sigm(a03 + bia[0][3]);
                cst0 = f0 * cst0 + i0 * g0;
                const float h0 = o0 * tanh_fast(cst0);

                const float i1 = sigm(a10 + bia[1][0]);
                const float f1 = sigm(a11 + bia[1][1]);
                const float g1 = tanh_fast(a12 + bia[1][2]);
                const float o1 = sigm(a13 + bia[1][3]);
                cst1 = f1 * cst1 + i1 * g1;
                const float h1v = o1 * tanh_fast(cst1);

                if (ct == 0) {
                    const unsigned long long t64 = (unsigned long long)(unsigned)(n + 1) << 32;
                    const size_t slot = (size_t)(n & (RD - 1)) * 512;
                    st_u64_sc1(&h1r[slot + hb + rt],      t64 | (unsigned long long)__float_as_uint(h0));
                    st_u64_sc1(&h1r[slot + hb + 16 + rt], t64 | (unsigned long long)__float_as_uint(h1v));
                }
            }

            __syncthreads();                   // off inter-WG critical path
            if (s_ab[0]) break;
            if (tid == 0) st_u32_sc1(&tags[role], (unsigned)(n + 1));
        }
    } else {
        // ========== LAYER 2: 16 h/WG; thread = 1 h x 4 gates x 20 cols =====
        const int hb2 = (role - L1WG) * 16;

        float wA[4][16], wB[4][4], bia[4];
#pragma unroll
        for (int q = 0; q < 4; ++q) {
            const int grow = q * 128 + hb2 + rt;
            const float4* pa = (const float4*)(Wih2 + (size_t)grow * 512 + ct * 16);
#pragma unroll
            for (int c = 0; c < 4; ++c) {
                float4 f = pa[c];
                wA[q][c * 4 + 0] = f.x; wA[q][c * 4 + 1] = f.y;
                wA[q][c * 4 + 2] = f.z; wA[q][c * 4 + 3] = f.w;
            }
            float4 b0 = *(const float4*)(Whh2 + (size_t)grow * 128 + ct * 4);
            wB[q][0] = b0.x; wB[q][1] = b0.y; wB[q][2] = b0.z; wB[q][3] = b0.w;
            bia[q] = bih2[grow] + bhh2[grow];
        }

        float cst = 0.0f;
        __syncthreads();   // s_ab visible

        for (int n = 1; n <= T_STEPS; ++n) {
            const int tau = n - 1;
            if (wave == 3 && n >= 8 && (n & 3) == 0 && lane < NWG) {
                const int thr = n - 3;
                unsigned sp = 0;
                for (;;) {
                    int ok = ((int)ld_u32_sc1(&tags[lane]) >= thr);
                    if (__all(ok)) break;
                    if ((++sp & 255u) == 0u) {
                        if (ld_u32_sc1(abf) != 0u) { s_ab[0] = 1u; break; }
                        if (sp >= (1u << 20)) { st_u32_sc1(abf, 1u); s_ab[0] = 1u; break; }
                    }
                }
            }

            float a0 = 0.f, a1 = 0.f, a2 = 0.f, a3 = 0.f;

            // ---- secondary first: h2[tau-1] (almost always ready) --------
            {
                const unsigned e2 = (unsigned)tau;
                const unsigned long long* p2 =
                    h2r + (size_t)((tau - 1) & (RD - 1)) * 128 + ct * 4;
                bool dn = false;
                unsigned sp = 0;
                for (;;) {
                    if (!dn) {
                        uint4v A, B;
                        ld2x16_sc1(p2, A, B);
                        if ((A.y == e2) & (A.w == e2) & (B.y == e2) & (B.w == e2)) {
                            const float s0 = __uint_as_float(A.x);
                            const float s1 = __uint_as_float(A.z);
                            const float s2 = __uint_as_float(B.x);
                            const float s3 = __uint_as_float(B.z);
                            a0 = fmaf(wB[0][0], s0, fmaf(wB[0][1], s1, fmaf(wB[0][2], s2, fmaf(wB[0][3], s3, a0))));
                            a1 = fmaf(wB[1][0], s0, fmaf(wB[1][1], s1, fmaf(wB[1][2], s2, fmaf(wB[1][3], s3, a1))));
                            a2 = fmaf(wB[2][0], s0, fmaf(wB[2][1], s1, fmaf(wB[2][2], s2, fmaf(wB[2][3], s3, a2))));
                            a3 = fmaf(wB[3][0], s0, fmaf(wB[3][1], s1, fmaf(wB[3][2], s2, fmaf(wB[3][3], s3, a3))));
                            dn = true;
                        }
                    }
                    if (__all(dn)) break;
                    if ((++sp & 63u) == 0u) {
                        if (ld_u32_sc1(abf) != 0u) { s_ab[0] = 1u; break; }
                        if (sp >= (1u << 20)) { st_u32_sc1(abf, 1u); s_ab[0] = 1u; break; }
                    }
                }
            }

            // ---- primary: h1[tau] (tag == n), FMA on arrival -------------
            {
                const unsigned e = (unsigned)n;
                const unsigned long long* p =
                    h1r + (size_t)(tau & (RD - 1)) * 512 + ct * 16;
                bool done = false;
                unsigned sp = 0;
                for (;;) {
                    if (!done) {
                        uint4v A0, A1, A2, A3, A4, A5, A6, A7;
                        ld8x16_sc1(p, A0, A1, A2, A3, A4, A5, A6, A7);
                        int ok = (A0.y == e) & (A0.w == e) & (A1.y == e) & (A1.w == e)
                               & (A2.y == e) & (A2.w == e) & (A3.y == e) & (A3.w == e)
                               & (A4.y == e) & (A4.w == e) & (A5.y == e) & (A5.w == e)
                               & (A6.y == e) & (A6.w == e) & (A7.y == e) & (A7.w == e);
                        if (ok) {
                            uint4v W[8] = { A0, A1, A2, A3, A4, A5, A6, A7 };
#pragma unroll
                            for (int k = 0; k < 8; ++k) {
                                const float v0 = __uint_as_float(W[k].x);
                                const float v1 = __uint_as_float(W[k].z);
                                a0 = fmaf(wA[0][2*k], v0, fmaf(wA[0][2*k+1], v1, a0));
                                a1 = fmaf(wA[1][2*k], v0, fmaf(wA[1][2*k+1], v1, a1));
                                a2 = fmaf(wA[2][2*k], v0, fmaf(wA[2][2*k+1], v1, a2));
                                a3 = fmaf(wA[3][2*k], v0, fmaf(wA[3][2*k+1], v1, a3));
                            }
                            done = true;
                        }
                    }
                    if (__all(done)) break;
                    if ((++sp & 63u) == 0u) {
                        if (ld_u32_sc1(abf) != 0u) { s_ab[0] = 1u; break; }
                        if (sp >= (1u << 20)) { st_u32_sc1(abf, 1u); s_ab[0] = 1u; break; }
                    }
                }
            }

            // ---- reduce over 32 ct lanes ---------------------------------
#pragma unroll
            for (int m = 16; m >= 1; m >>= 1) {
                a0 += __shfl_xor(a0, m, 64); a1 += __shfl_xor(a1, m, 64);
                a2 += __shfl_xor(a2, m, 64); a3 += __shfl_xor(a3, m, 64);
            }

            // ---- activation + publish ------------------------------------
            {
                const float ii = sigm(a0 + bia[0]);
                const float ff = sigm(a1 + bia[1]);
                const float gg = tanh_fast(a2 + bia[2]);
                const float oo = sigm(a3 + bia[3]);
                cst = ff * cst + ii * gg;
                const float h = oo * tanh_fast(cst);

                if (ct == 0) {
                    const unsigned long long pair =
                        ((unsigned long long)(unsigned)n << 32) |
                        (unsigned long long)__float_as_uint(h);
                    st_u64_sc1(&h2r[(size_t)(tau & (RD - 1)) * 128 + hb2 + rt], pair);
                    out[(size_t)tau * 128 + hb2 + rt] = h;
                }
            }

            __syncthreads();
            if (s_ab[0]) break;
            if (tid == 0) st_u32_sc1(&tags[role], (unsigned)(n + 1));
        }
    }
}

extern "C" void kernel_launch(void* const* d_in, const int* in_sizes, int n_in,
                              void* d_out, int out_size, void* d_ws, size_t ws_size,
                              hipStream_t stream)
{
    const float* x    = (const float*)d_in[0];
    const float* Wih1 = (const float*)d_in[1];
    const float* Whh1 = (const float*)d_in[2];
    const float* bih1 = (const float*)d_in[3];
    const float* bhh1 = (const float*)d_in[4];
    const float* Wih2 = (const float*)d_in[5];
    const float* Whh2 = (const float*)d_in[6];
    const float* bih2 = (const float*)d_in[7];
    const float* bhh2 = (const float*)d_in[8];
    unsigned int* ws  = (unsigned int*)d_ws;

    hipLaunchKernelGGL(lstm_init, dim3(44), dim3(256), 0, stream, ws);
    hipLaunchKernelGGL(lstm_persist, dim3(NWG), dim3(BLK), 0, stream,
                       x, Wih1, Whh1, bih1, bhh1, Wih2, Whh2, bih2, bhh2,
                       (float*)d_out, ws);
}

// Round 13
// 90315.540 us; speedup vs baseline: 1.4613x; 1.4613x over previous
//
#include <hip/hip_runtime.h>
#include <math.h>

// ---------------------------------------------------------------------------
// 2-layer LSTM, batch=1, T=32768, I=128, H=512  (PyTorch gate order i,f,g,o)
//
// 24 persistent WGs x 512 threads (grid == 24).
//   WG 0..15  : layer-1, WG k owns h1[k*32 .. k*32+32)
//   WG 16..23 : layer-2, WG j owns h2[(j-16)*16 ..+16), runs 1 step behind.
//
// Protocol: (tag<<32)|f32bits u64 words in depth-8 rings, device-scope sc1.
// Consumers poll the sc1 ring EVERY spin (detection within ~1 RT of store
// visibility — r7's sc0 spin+merge-every-8 left ~1500cy of blind time per
// detect since sc0 never delivers cross-XCD). Per-lane early-exit: a lane
// whose 4 tags matched stages to LDS and stops issuing loads. This is r8's
// poll structure WITHOUT r8's PIN pragmas (those forced scratch spills,
// VGPR 104 + 0.9GB spill traffic, poisoning the measurement). Weights are
// plain arrays exactly as r7 (best measured, 86.8ms).
// Overwrite guard (tags >= n-3) in wave 3, every 4th step, off crit path.
// One __syncthreads per step; double-buffered LDS operand staging.
// ---------------------------------------------------------------------------

#define T_STEPS 32768
#define L1WG    16
#define NWG     24
#define BLK     512
#define RD      8

// ws u32 layout
#define ABT_OFF  9
#define TAG_OFF  32                      // tags[24]
#define H1_OFF   1024                    // u64[RD][512] -> 8192 u32
#define H2_OFF   (H1_OFF + RD * 512 * 2) // u64[RD][128] -> 2048 u32
#define WS_WORDS (H2_OFF + RD * 128 * 2) // 11264 u32 = 45 KB

typedef unsigned int uint4v __attribute__((ext_vector_type(4)));

__device__ __forceinline__ float sigm(float x) { return 1.0f / (1.0f + __expf(-x)); }
__device__ __forceinline__ float tanh_fast(float x) { return 1.0f - 2.0f / (__expf(2.0f * x) + 1.0f); }

// ---- device-scope (sc1) access helpers -----------------------------------
__device__ __forceinline__ unsigned ld_u32_sc1(const unsigned* p) {
    unsigned r;
    asm volatile("global_load_dword %0, %1, off sc1\n\ts_waitcnt vmcnt(0)"
                 : "=v"(r) : "v"(p) : "memory");
    return r;
}
__device__ __forceinline__ void st_u32_sc1(unsigned* p, unsigned v) {
    asm volatile("global_store_dword %0, %1, off sc1" :: "v"(p), "v"(v) : "memory");
}
__device__ __forceinline__ void st_u64_sc1(unsigned long long* p, unsigned long long v) {
    asm volatile("global_store_dwordx2 %0, %1, off sc1" :: "v"(p), "v"(v) : "memory");
}
__device__ __forceinline__ void ld2x16_sc1(const unsigned long long* p, uint4v& A, uint4v& B) {
    asm volatile("global_load_dwordx4 %0, %2, off sc1\n\t"
                 "global_load_dwordx4 %1, %3, off sc1\n\t"
                 "s_waitcnt vmcnt(0)"
                 : "=&v"(A), "=&v"(B) : "v"(p), "v"(p + 2) : "memory");
}
__device__ __forceinline__ void ld1x16_sc1(const unsigned long long* p, uint4v& A) {
    asm volatile("global_load_dwordx4 %0, %1, off sc1\n\ts_waitcnt vmcnt(0)"
                 : "=&v"(A) : "v"(p) : "memory");
}

__global__ void lstm_init(unsigned int* ws)
{
    int i = blockIdx.x * blockDim.x + threadIdx.x;
    if (i < WS_WORDS) ws[i] = 0u;
}

__global__ __launch_bounds__(BLK, 2) void lstm_persist(
    const float* __restrict__ x,      // [32768][128]
    const float* __restrict__ Wih1,   // [2048][128]
    const float* __restrict__ Whh1,   // [2048][512]
    const float* __restrict__ bih1,
    const float* __restrict__ bhh1,
    const float* __restrict__ Wih2,   // [512][512]
    const float* __restrict__ Whh2,   // [512][128]
    const float* __restrict__ bih2,
    const float* __restrict__ bhh2,
    float* __restrict__ out,          // [32768][128]
    unsigned int* ws)
{
    const int role = blockIdx.x;      // 0..23
    const int tid  = threadIdx.x;
    const int wave = tid >> 6;
    const int lane = tid & 63;

    __shared__ __align__(16) float h1buf[2][32 * 20];   // entry stride 20
    __shared__ __align__(16) float h2buf[2][8 * 20];
    __shared__ unsigned s_ab[1];

    unsigned* abf  = ws + ABT_OFF;
    unsigned* tags = ws + TAG_OFF;
    unsigned long long* h1r = (unsigned long long*)(ws + H1_OFF);
    unsigned long long* h2r = (unsigned long long*)(ws + H2_OFF);

    if (tid == 0) s_ab[0] = 0u;

    const bool isL1 = role < L1WG;

    if (isL1) {
        // ================= LAYER 1: 32 h-indices per WG ====================
        const int rt = tid >> 4;          // 0..31 h-index
        const int ct = tid & 15;          // 0..15 col-tile (32 prim + 8 sec)
        const int hb = role * 32;

        float wA[4][32], wB[4][8], bia[4];
#pragma unroll
        for (int q = 0; q < 4; ++q) {
            const int grow = q * 512 + hb + rt;
            const float4* pa = (const float4*)(Whh1 + (size_t)grow * 512 + ct * 32);
#pragma unroll
            for (int c = 0; c < 8; ++c) {
                float4 f = pa[c];
                wA[q][c * 4 + 0] = f.x; wA[q][c * 4 + 1] = f.y;
                wA[q][c * 4 + 2] = f.z; wA[q][c * 4 + 3] = f.w;
            }
            const float4* pb = (const float4*)(Wih1 + (size_t)grow * 128 + ct * 8);
            float4 b0 = pb[0], b1 = pb[1];
            wB[q][0] = b0.x; wB[q][1] = b0.y; wB[q][2] = b0.z; wB[q][3] = b0.w;
            wB[q][4] = b1.x; wB[q][5] = b1.y; wB[q][6] = b1.z; wB[q][7] = b1.w;
            bia[q] = bih1[grow] + bhh1[grow];
        }

        float cst = 0.0f;
        float4 vx0 = *(const float4*)(x + ct * 8);
        float4 vx1 = *(const float4*)(x + ct * 8 + 4);
        __syncthreads();   // s_ab visible

        for (int n = 0; n < T_STEPS; ++n) {
            // ---- wave 3: overwrite guard, every 4th step, off crit path --
            if (wave == 3 && n >= 8 && (n & 3) == 0 && lane < NWG) {
                const int thr = n - 3;
                unsigned sp = 0;
                for (;;) {
                    int ok = ((int)ld_u32_sc1(&tags[lane]) >= thr);
                    if (__all(ok)) break;
                    if ((++sp & 255u) == 0u) {
                        if (ld_u32_sc1(abf) != 0u) { s_ab[0] = 1u; break; }
                        if (sp >= (1u << 21)) { st_u32_sc1(abf, 1u); s_ab[0] = 1u; break; }
                    }
                }
            }
            // ---- waves 0/1: poll+stage h1[n-1] (tag == n), early-exit ----
            if (wave < 2) {
                const size_t off = (size_t)((n - 1) & (RD - 1)) * 512 + wave * 256 + lane * 4;
                const unsigned long long* p = h1r + off;
                const unsigned e = (unsigned)n;
                const int g = wave * 256 + lane * 4;
                bool done = false;
                unsigned sp = 0;
                for (;;) {
                    if (!done) {
                        uint4v A, B;
                        ld2x16_sc1(p, A, B);
                        if ((A.y == e) & (A.w == e) & (B.y == e) & (B.w == e)) {
                            float4 vals = make_float4(
                                __uint_as_float(A.x), __uint_as_float(A.z),
                                __uint_as_float(B.x), __uint_as_float(B.z));
                            *(float4*)&h1buf[n & 1][(g >> 4) * 20 + (g & 15)] = vals;
                            done = true;
                        }
                    }
                    if (__all(done)) break;
                    if ((++sp & 255u) == 0u) {
                        if (ld_u32_sc1(abf) != 0u) { s_ab[0] = 1u; break; }
                        if (sp >= (1u << 20)) { st_u32_sc1(abf, 1u); s_ab[0] = 1u; break; }
                    }
                }
            }

            __syncthreads();
            if (s_ab[0]) break;
            if (tid == 0) st_u32_sc1(&tags[role], (unsigned)(n + 1));

            // ---- compute: 4 gates x (32 prim + 8 sec) cols ---------------
            float acc0 = 0.f, acc1 = 0.f, acc2 = 0.f, acc3 = 0.f;
            const float* hv = &h1buf[n & 1][(ct * 2) * 20];      // 32 cols = 2 entries
#pragma unroll
            for (int c = 0; c < 4; ++c) {
                float4 h4 = *(const float4*)(hv + c * 4);
                acc0 = fmaf(wA[0][c*4+0], h4.x, acc0); acc0 = fmaf(wA[0][c*4+1], h4.y, acc0);
                acc0 = fmaf(wA[0][c*4+2], h4.z, acc0); acc0 = fmaf(wA[0][c*4+3], h4.w, acc0);
                acc1 = fmaf(wA[1][c*4+0], h4.x, acc1); acc1 = fmaf(wA[1][c*4+1], h4.y, acc1);
                acc1 = fmaf(wA[1][c*4+2], h4.z, acc1); acc1 = fmaf(wA[1][c*4+3], h4.w, acc1);
                acc2 = fmaf(wA[2][c*4+0], h4.x, acc2); acc2 = fmaf(wA[2][c*4+1], h4.y, acc2);
                acc2 = fmaf(wA[2][c*4+2], h4.z, acc2); acc2 = fmaf(wA[2][c*4+3], h4.w, acc2);
                acc3 = fmaf(wA[3][c*4+0], h4.x, acc3); acc3 = fmaf(wA[3][c*4+1], h4.y, acc3);
                acc3 = fmaf(wA[3][c*4+2], h4.z, acc3); acc3 = fmaf(wA[3][c*4+3], h4.w, acc3);
            }
            const float* hv2 = &h1buf[n & 1][(ct * 2 + 1) * 20];
#pragma unroll
            for (int c = 0; c < 4; ++c) {
                float4 h4 = *(const float4*)(hv2 + c * 4);
                acc0 = fmaf(wA[0][16+c*4+0], h4.x, acc0); acc0 = fmaf(wA[0][16+c*4+1], h4.y, acc0);
                acc0 = fmaf(wA[0][16+c*4+2], h4.z, acc0); acc0 = fmaf(wA[0][16+c*4+3], h4.w, acc0);
                acc1 = fmaf(wA[1][16+c*4+0], h4.x, acc1); acc1 = fmaf(wA[1][16+c*4+1], h4.y, acc1);
                acc1 = fmaf(wA[1][16+c*4+2], h4.z, acc1); acc1 = fmaf(wA[1][16+c*4+3], h4.w, acc1);
                acc2 = fmaf(wA[2][16+c*4+0], h4.x, acc2); acc2 = fmaf(wA[2][16+c*4+1], h4.y, acc2);
                acc2 = fmaf(wA[2][16+c*4+2], h4.z, acc2); acc2 = fmaf(wA[2][16+c*4+3], h4.w, acc2);
                acc3 = fmaf(wA[3][16+c*4+0], h4.x, acc3); acc3 = fmaf(wA[3][16+c*4+1], h4.y, acc3);
                acc3 = fmaf(wA[3][16+c*4+2], h4.z, acc3); acc3 = fmaf(wA[3][16+c*4+3], h4.w, acc3);
            }
            {
                const float sx[8] = { vx0.x, vx0.y, vx0.z, vx0.w,
                                      vx1.x, vx1.y, vx1.z, vx1.w };
#pragma unroll
                for (int j = 0; j < 8; ++j) {
                    acc0 = fmaf(wB[0][j], sx[j], acc0);
                    acc1 = fmaf(wB[1][j], sx[j], acc1);
                    acc2 = fmaf(wB[2][j], sx[j], acc2);
                    acc3 = fmaf(wB[3][j], sx[j], acc3);
                }
            }
            {   // prefetch next x row
                const int tn = (n + 1 < T_STEPS) ? (n + 1) : (T_STEPS - 1);
                vx0 = *(const float4*)(x + (size_t)tn * 128 + ct * 8);
                vx1 = *(const float4*)(x + (size_t)tn * 128 + ct * 8 + 4);
            }
#pragma unroll
            for (int m = 8; m >= 1; m >>= 1) {
                acc0 += __shfl_xor(acc0, m, 64);
                acc1 += __shfl_xor(acc1, m, 64);
                acc2 += __shfl_xor(acc2, m, 64);
                acc3 += __shfl_xor(acc3, m, 64);
            }
            const float ii = sigm(acc0 + bia[0]);
            const float ff = sigm(acc1 + bia[1]);
            const float g2 = tanh_fast(acc2 + bia[2]);
            const float oo = sigm(acc3 + bia[3]);
            cst = ff * cst + ii * g2;
            const float h = oo * tanh_fast(cst);

            if (ct == 0) {
                const unsigned long long pair =
                    ((unsigned long long)(unsigned)(n + 1) << 32) |
                    (unsigned long long)__float_as_uint(h);
                st_u64_sc1(&h1r[(size_t)(n & (RD - 1)) * 512 + hb + rt], pair);
            }
        }
    } else {
        // ================= LAYER 2: 16 h-indices per WG ====================
        const int rt  = tid >> 5;         // 0..15
        const int ct  = tid & 31;         // 0..31 (16 prim + 4 sec cols)
        const int hb2 = (role - L1WG) * 16;

        float wA[4][16], wB[4][4], bia[4];
#pragma unroll
        for (int q = 0; q < 4; ++q) {
            const int grow = q * 128 + hb2 + rt;
            const float4* pa = (const float4*)(Wih2 + (size_t)grow * 512 + ct * 16);
#pragma unroll
            for (int c = 0; c < 4; ++c) {
                float4 f = pa[c];
                wA[q][c * 4 + 0] = f.x; wA[q][c * 4 + 1] = f.y;
                wA[q][c * 4 + 2] = f.z; wA[q][c * 4 + 3] = f.w;
            }
            float4 b0 = *(const float4*)(Whh2 + (size_t)grow * 128 + ct * 4);
            wB[q][0] = b0.x; wB[q][1] = b0.y; wB[q][2] = b0.z; wB[q][3] = b0.w;
            bia[q] = bih2[grow] + bhh2[grow];
        }

        float cst = 0.0f;
        __syncthreads();   // s_ab visible

        for (int n = 1; n <= T_STEPS; ++n) {
            const int tau = n - 1;
            if (wave == 3 && n >= 8 && (n & 3) == 0 && lane < NWG) {
                const int thr = n - 3;
                unsigned sp = 0;
                for (;;) {
                    int ok = ((int)ld_u32_sc1(&tags[lane]) >= thr);
                    if (__all(ok)) break;
                    if ((++sp & 255u) == 0u) {
                        if (ld_u32_sc1(abf) != 0u) { s_ab[0] = 1u; break; }
                        if (sp >= (1u << 21)) { st_u32_sc1(abf, 1u); s_ab[0] = 1u; break; }
                    }
                }
            }
            // ---- waves 0/1: poll+stage h1[tau] (tag == n), early-exit ----
            if (wave < 2) {
                const size_t off = (size_t)(tau & (RD - 1)) * 512 + wave * 256 + lane * 4;
                const unsigned long long* p = h1r + off;
                const unsigned e = (unsigned)n;
                const int g = wave * 256 + lane * 4;
                bool done = false;
                unsigned sp = 0;
                for (;;) {
                    if (!done) {
                        uint4v A, B;
                        ld2x16_sc1(p, A, B);
                        if ((A.y == e) & (A.w == e) & (B.y == e) & (B.w == e)) {
                            float4 vals = make_float4(
                                __uint_as_float(A.x), __uint_as_float(A.z),
                                __uint_as_float(B.x), __uint_as_float(B.z));
                            *(float4*)&h1buf[n & 1][(g >> 4) * 20 + (g & 15)] = vals;
                            done = true;
                        }
                    }
                    if (__all(done)) break;
                    if ((++sp & 255u) == 0u) {
                        if (ld_u32_sc1(abf) != 0u) { s_ab[0] = 1u; break; }
                        if (sp >= (1u << 20)) { st_u32_sc1(abf, 1u); s_ab[0] = 1u; break; }
                    }
                }
            }
            // ---- wave 2: poll+stage h2[tau-1] (tag == tau), early-exit ---
            if (wave == 2) {
                const size_t off = (size_t)((tau - 1) & (RD - 1)) * 128 + lane * 2;
                const unsigned long long* p = h2r + off;
                const unsigned e = (unsigned)tau;
                const int pi = lane * 2;
                bool done = false;
                unsigned sp = 0;
                for (;;) {
                    if (!done) {
                        uint4v A;
                        ld1x16_sc1(p, A);
                        if ((A.y == e) & (A.w == e)) {
                            float2 v2 = make_float2(__uint_as_float(A.x),
                                                    __uint_as_float(A.z));
                            *(float2*)&h2buf[n & 1][(pi >> 4) * 20 + (pi & 15)] = v2;
                            done = true;
                        }
                    }
                    if (__all(done)) break;
                    if ((++sp & 255u) == 0u) {
                        if (ld_u32_sc1(abf) != 0u) { s_ab[0] = 1u; break; }
                        if (sp >= (1u << 20)) { st_u32_sc1(abf, 1u); s_ab[0] = 1u; break; }
                    }
                }
            }

            __syncthreads();
            if (s_ab[0]) break;
            if (tid == 0) st_u32_sc1(&tags[role], (unsigned)(n + 1));

            // ---- compute: 4 gates x (16 prim + 4 sec) --------------------
            float acc0 = 0.f, acc1 = 0.f, acc2 = 0.f, acc3 = 0.f;
            const float* hv = &h1buf[n & 1][ct * 20];
#pragma unroll
            for (int c = 0; c < 4; ++c) {
                float4 h4 = *(const float4*)(hv + c * 4);
                acc0 = fmaf(wA[0][c*4+0], h4.x, acc0); acc0 = fmaf(wA[0][c*4+1], h4.y, acc0);
                acc0 = fmaf(wA[0][c*4+2], h4.z, acc0); acc0 = fmaf(wA[0][c*4+3], h4.w, acc0);
                acc1 = fmaf(wA[1][c*4+0], h4.x, acc1); acc1 = fmaf(wA[1][c*4+1], h4.y, acc1);
                acc1 = fmaf(wA[1][c*4+2], h4.z, acc1); acc1 = fmaf(wA[1][c*4+3], h4.w, acc1);
                acc2 = fmaf(wA[2][c*4+0], h4.x, acc2); acc2 = fmaf(wA[2][c*4+1], h4.y, acc2);
                acc2 = fmaf(wA[2][c*4+2], h4.z, acc2); acc2 = fmaf(wA[2][c*4+3], h4.w, acc2);
                acc3 = fmaf(wA[3][c*4+0], h4.x, acc3); acc3 = fmaf(wA[3][c*4+1], h4.y, acc3);
                acc3 = fmaf(wA[3][c*4+2], h4.z, acc3); acc3 = fmaf(wA[3][c*4+3], h4.w, acc3);
            }
            {
                float4 s4 = *(const float4*)&h2buf[n & 1][(ct >> 2) * 20 + (ct & 3) * 4];
                const float sv[4] = { s4.x, s4.y, s4.z, s4.w };
#pragma unroll
                for (int j = 0; j < 4; ++j) {
                    acc0 = fmaf(wB[0][j], sv[j], acc0);
                    acc1 = fmaf(wB[1][j], sv[j], acc1);
                    acc2 = fmaf(wB[2][j], sv[j], acc2);
                    acc3 = fmaf(wB[3][j], sv[j], acc3);
                }
            }
#pragma unroll
            for (int m = 16; m >= 1; m >>= 1) {
                acc0 += __shfl_xor(acc0, m, 64);
                acc1 += __shfl_xor(acc1, m, 64);
                acc2 += __shfl_xor(acc2, m, 64);
                acc3 += __shfl_xor(acc3, m, 64);
            }
            const float ii = sigm(acc0 + bia[0]);
            const float ff = sigm(acc1 + bia[1]);
            const float g2 = tanh_fast(acc2 + bia[2]);
            const float oo = sigm(acc3 + bia[3]);
            cst = ff * cst + ii * g2;
            const float h = oo * tanh_fast(cst);

            if (ct == 0) {
                const unsigned long long pair =
                    ((unsigned long long)(unsigned)n << 32) |
                    (unsigned long long)__float_as_uint(h);
                st_u64_sc1(&h2r[(size_t)(tau & (RD - 1)) * 128 + hb2 + rt], pair);
                out[(size_t)tau * 128 + hb2 + rt] = h;
            }
        }
    }
}

extern "C" void kernel_launch(void* const* d_in, const int* in_sizes, int n_in,
                              void* d_out, int out_size, void* d_ws, size_t ws_size,
                              hipStream_t stream)
{
    const float* x    = (const float*)d_in[0];
    const float* Wih1 = (const float*)d_in[1];
    const float* Whh1 = (const float*)d_in[2];
    const float* bih1 = (const float*)d_in[3];
    const float* bhh1 = (const float*)d_in[4];
    const float* Wih2 = (const float*)d_in[5];
    const float* Whh2 = (const float*)d_in[6];
    const float* bih2 = (const float*)d_in[7];
    const float* bhh2 = (const float*)d_in[8];
    unsigned int* ws  = (unsigned int*)d_ws;

    hipLaunchKernelGGL(lstm_init, dim3(44), dim3(256), 0, stream, ws);
    hipLaunchKernelGGL(lstm_persist, dim3(NWG), dim3(BLK), 0, stream,
                       x, Wih1, Whh1, bih1, bhh1, Wih2, Whh2, bih2, bhh2,
                       (float*)d_out, ws);
}

// Round 14
// 86522.003 us; speedup vs baseline: 1.5254x; 1.0438x over previous
//
#include <hip/hip_runtime.h>
#include <math.h>

// ---------------------------------------------------------------------------
// 2-layer LSTM, batch=1, T=32768, I=128, H=512  (PyTorch gate order i,f,g,o)
//
// FINAL KERNEL — byte-for-byte revert to round 7, the best-measured variant
// (86.8 ms, ~2.65 us/step). 13 rounds of structural exploration (staged vs
// direct consumption, 24/40-WG decompositions, sc0/sc1 poll cadences, AGPR/
// PIN residency, barrier placement, thread scaling) all converged to ~2.65
// us/step or worse: the step period is pinned by the irreducible cross-XCD
// publish->L3->detect latency chain (per-XCD L2s are non-coherent) plus a
// ~1 us serial compute tail that resists wider decomposition (straggler-max
// over lockstep WGs) — a latency floor, not a bandwidth/compute roofline.
//
// Structure: 256 WGs launched; election picks 24 workers on one XCD (with
// pigeonhole ticket scheme; correctness does NOT depend on it). 16 L1 WGs
// (32 h each) + 8 L2 WGs (16 h each, one step behind). Handoff words are
// (tag<<32)|f32bits u64 in depth-8 rings, dual-published sc0+sc1; consumers
// spin on sc0 (cheap local-L2 backoff that keeps the fabric quiet) and merge
// from the guaranteed sc1 ring every 8th spin. Overwrite guard (tags>=n-3)
// in idle wave 3 every 4th step, off the critical path. One barrier/step.
// ---------------------------------------------------------------------------

#define T_STEPS 32768
#define L1WG    16
#define NWG     24
#define BLK     512
#define GRID    256
#define RD      8

// ws u32 layout
#define CNT_OFF  0                         // [0..7] per-XCD ticket counters
#define CHO_OFF  8                         // elected xcd+1 (0 = unset)
#define ABT_OFF  9                         // abort flag
#define TAG_OFF  32                        // tags[24]
#define H1F_OFF  1024                      // u64[RD][512] fast  (8192 u32)
#define H1S_OFF  (H1F_OFF + RD * 512 * 2)  // u64[RD][512] slow
#define H2F_OFF  (H1S_OFF + RD * 512 * 2)  // u64[RD][128] fast  (2048 u32)
#define H2S_OFF  (H2F_OFF + RD * 128 * 2)  // u64[RD][128] slow
#define WS_WORDS (H2S_OFF + RD * 128 * 2)  // 21504 u32 = 86 KB

typedef unsigned int uint4v __attribute__((ext_vector_type(4)));

__device__ __forceinline__ float sigm(float x) { return 1.0f / (1.0f + __expf(-x)); }
__device__ __forceinline__ float tanh_fast(float x) { return 1.0f - 2.0f / (__expf(2.0f * x) + 1.0f); }

// ---- scoped access helpers ------------------------------------------------
__device__ __forceinline__ unsigned ld_u32_sc1(const unsigned* p) {
    unsigned r;
    asm volatile("global_load_dword %0, %1, off sc1\n\ts_waitcnt vmcnt(0)"
                 : "=v"(r) : "v"(p) : "memory");
    return r;
}
__device__ __forceinline__ void st_u32_sc1(unsigned* p, unsigned v) {
    asm volatile("global_store_dword %0, %1, off sc1" :: "v"(p), "v"(v) : "memory");
}
__device__ __forceinline__ void st_u64_sc0(unsigned long long* p, unsigned long long v) {
    asm volatile("global_store_dwordx2 %0, %1, off sc0" :: "v"(p), "v"(v) : "memory");
}
__device__ __forceinline__ void st_u64_sc1(unsigned long long* p, unsigned long long v) {
    asm volatile("global_store_dwordx2 %0, %1, off sc1" :: "v"(p), "v"(v) : "memory");
}
__device__ __forceinline__ void ld2x16_sc0(const unsigned long long* p, uint4v& A, uint4v& B) {
    asm volatile("global_load_dwordx4 %0, %2, off sc0\n\t"
                 "global_load_dwordx4 %1, %3, off sc0\n\t"
                 "s_waitcnt vmcnt(0)"
                 : "=&v"(A), "=&v"(B) : "v"(p), "v"(p + 2) : "memory");
}
__device__ __forceinline__ void ld2x16_sc1(const unsigned long long* p, uint4v& A, uint4v& B) {
    asm volatile("global_load_dwordx4 %0, %2, off sc1\n\t"
                 "global_load_dwordx4 %1, %3, off sc1\n\t"
                 "s_waitcnt vmcnt(0)"
                 : "=&v"(A), "=&v"(B) : "v"(p), "v"(p + 2) : "memory");
}
__device__ __forceinline__ void ld1x16_sc0(const unsigned long long* p, uint4v& A) {
    asm volatile("global_load_dwordx4 %0, %1, off sc0\n\ts_waitcnt vmcnt(0)"
                 : "=&v"(A) : "v"(p) : "memory");
}
__device__ __forceinline__ void ld1x16_sc1(const unsigned long long* p, uint4v& A) {
    asm volatile("global_load_dwordx4 %0, %1, off sc1\n\ts_waitcnt vmcnt(0)"
                 : "=&v"(A) : "v"(p) : "memory");
}

__global__ void lstm_init(unsigned int* ws)
{
    int i = blockIdx.x * blockDim.x + threadIdx.x;
    if (i < WS_WORDS) ws[i] = 0u;
}

__global__ __launch_bounds__(BLK) void lstm_persist(
    const float* __restrict__ x,      // [32768][128]
    const float* __restrict__ Wih1,   // [2048][128]
    const float* __restrict__ Whh1,   // [2048][512]
    const float* __restrict__ bih1,
    const float* __restrict__ bhh1,
    const float* __restrict__ Wih2,   // [512][512]
    const float* __restrict__ Whh2,   // [512][128]
    const float* __restrict__ bih2,
    const float* __restrict__ bhh2,
    float* __restrict__ out,          // [32768][128]
    unsigned int* ws)
{
    const int tid  = threadIdx.x;
    const int wave = tid >> 6;
    const int lane = tid & 63;

    __shared__ __align__(16) float h1buf[2][16 * 36];   // chunked, stride 36
    __shared__ __align__(16) float h2buf[2][8 * 20];    // entry stride 20
    __shared__ unsigned s_role[1];
    __shared__ unsigned s_ab[1];

    unsigned* cnt  = ws + CNT_OFF;
    unsigned* cho  = ws + CHO_OFF;
    unsigned* abf  = ws + ABT_OFF;
    unsigned* tags = ws + TAG_OFF;
    unsigned long long* h1f = (unsigned long long*)(ws + H1F_OFF);
    unsigned long long* h1s = (unsigned long long*)(ws + H1S_OFF);
    unsigned long long* h2f = (unsigned long long*)(ws + H2F_OFF);
    unsigned long long* h2s = (unsigned long long*)(ws + H2S_OFF);

    // ---- election: first XCD to accumulate NWG tickets wins --------------
    if (tid == 0) {
        s_ab[0] = 0u;
        unsigned xcc;
        asm volatile("s_getreg_b32 %0, hwreg(20, 0, 32)" : "=s"(xcc));  // XCC_ID
        xcc &= 7u;
        unsigned role = 0xFFFFu;
        unsigned tkt = __hip_atomic_fetch_add(&cnt[xcc], 1u,
                           __ATOMIC_RELAXED, __HIP_MEMORY_SCOPE_AGENT);
        if (tkt < NWG) {
            if (tkt == NWG - 1) {
                unsigned exp = 0u;
                __hip_atomic_compare_exchange_strong(cho, &exp, xcc + 1u,
                    __ATOMIC_RELAXED, __ATOMIC_RELAXED, __HIP_MEMORY_SCOPE_AGENT);
            }
            unsigned c, sp = 0;
            for (;;) {
                c = __hip_atomic_load(cho, __ATOMIC_RELAXED, __HIP_MEMORY_SCOPE_AGENT);
                if (c != 0u) break;
                __builtin_amdgcn_s_sleep(2);
                if (++sp > (1u << 22)) { c = 0xFFu; break; }
            }
            if (c == xcc + 1u) role = tkt;
        }
        s_role[0] = role;
    }
    __syncthreads();
    const int role = (int)s_role[0];
    if (role >= NWG) return;

    const bool isL1 = role < L1WG;

    if (isL1) {
        // ================= LAYER 1: 32 h-indices per WG ====================
        const int rt = tid >> 4;          // 0..31 h-index
        const int ct = tid & 15;          // 0..15 col-tile (32 prim + 8 sec)
        const int hb = role * 32;

        float wA[4][32], wB[4][8], bia[4];
#pragma unroll
        for (int q = 0; q < 4; ++q) {
            const int grow = q * 512 + hb + rt;
            const float4* pa = (const float4*)(Whh1 + (size_t)grow * 512 + ct * 32);
#pragma unroll
            for (int c = 0; c < 8; ++c) {
                float4 f = pa[c];
                wA[q][c * 4 + 0] = f.x; wA[q][c * 4 + 1] = f.y;
                wA[q][c * 4 + 2] = f.z; wA[q][c * 4 + 3] = f.w;
            }
            const float4* pb = (const float4*)(Wih1 + (size_t)grow * 128 + ct * 8);
            float4 b0 = pb[0], b1 = pb[1];
            wB[q][0] = b0.x; wB[q][1] = b0.y; wB[q][2] = b0.z; wB[q][3] = b0.w;
            wB[q][4] = b1.x; wB[q][5] = b1.y; wB[q][6] = b1.z; wB[q][7] = b1.w;
            bia[q] = bih1[grow] + bhh1[grow];
        }

        float cst = 0.0f;
        float4 vx0 = *(const float4*)(x + ct * 8);
        float4 vx1 = *(const float4*)(x + ct * 8 + 4);
        __syncthreads();   // s_ab visible

        for (int n = 0; n < T_STEPS; ++n) {
            // ---- wave 3: overwrite guard, every 4th step, off crit path --
            if (wave == 3 && n >= 8 && (n & 3) == 0 && lane < NWG) {
                const int thr = n - 3;
                unsigned sp = 0;
                for (;;) {
                    int ok = ((int)ld_u32_sc1(&tags[lane]) >= thr);
                    if (__all(ok)) break;
                    if ((++sp & 255u) == 0u) {
                        if (ld_u32_sc1(abf) != 0u) { s_ab[0] = 1u; break; }
                        if (sp >= (1u << 21)) { st_u32_sc1(abf, 1u); s_ab[0] = 1u; break; }
                    }
                }
            }
            // ---- waves 0/1: poll+merge+stage h1[n-1] (tag == n) ----------
            if (wave < 2) {
                const size_t off = (size_t)((n - 1) & (RD - 1)) * 512 + wave * 256 + lane * 4;
                const unsigned long long* pf = h1f + off;
                const unsigned long long* ps = h1s + off;
                const unsigned e = (unsigned)n;
                uint4v A, B;
                unsigned sp = 0;
                for (;;) {
                    ld2x16_sc0(pf, A, B);
                    int ok = (A.y == e) & (A.w == e) & (B.y == e) & (B.w == e);
                    if (__all(ok)) break;
                    if ((++sp & 7u) == 0u) {
                        uint4v C, D;
                        ld2x16_sc1(ps, C, D);
                        if (A.y != e) { A.x = C.x; A.y = C.y; }
                        if (A.w != e) { A.z = C.z; A.w = C.w; }
                        if (B.y != e) { B.x = D.x; B.y = D.y; }
                        if (B.w != e) { B.z = D.z; B.w = D.w; }
                        ok = (A.y == e) & (A.w == e) & (B.y == e) & (B.w == e);
                        if (__all(ok)) break;
                        if ((sp & 2047u) == 0u) {
                            if (ld_u32_sc1(abf) != 0u) { s_ab[0] = 1u; break; }
                            if (sp >= (1u << 22)) { st_u32_sc1(abf, 1u); s_ab[0] = 1u; break; }
                        }
                    }
                }
                const int g = wave * 256 + lane * 4;
                float4 vals = make_float4(__uint_as_float(A.x), __uint_as_float(A.z),
                                          __uint_as_float(B.x), __uint_as_float(B.z));
                *(float4*)&h1buf[n & 1][(g >> 5) * 36 + (g & 31)] = vals;
            }

            __syncthreads();
            if (s_ab[0]) break;
            if (tid == 0) st_u32_sc1(&tags[role], (unsigned)(n + 1));

            // ---- compute: 4 gates x (32 prim + 8 sec) cols ---------------
            float acc0 = 0.f, acc1 = 0.f, acc2 = 0.f, acc3 = 0.f;
            const float* hv = &h1buf[n & 1][ct * 36];
#pragma unroll
            for (int c = 0; c < 8; ++c) {
                float4 h4 = *(const float4*)(hv + c * 4);
                acc0 = fmaf(wA[0][c*4+0], h4.x, acc0); acc0 = fmaf(wA[0][c*4+1], h4.y, acc0);
                acc0 = fmaf(wA[0][c*4+2], h4.z, acc0); acc0 = fmaf(wA[0][c*4+3], h4.w, acc0);
                acc1 = fmaf(wA[1][c*4+0], h4.x, acc1); acc1 = fmaf(wA[1][c*4+1], h4.y, acc1);
                acc1 = fmaf(wA[1][c*4+2], h4.z, acc1); acc1 = fmaf(wA[1][c*4+3], h4.w, acc1);
                acc2 = fmaf(wA[2][c*4+0], h4.x, acc2); acc2 = fmaf(wA[2][c*4+1], h4.y, acc2);
                acc2 = fmaf(wA[2][c*4+2], h4.z, acc2); acc2 = fmaf(wA[2][c*4+3], h4.w, acc2);
                acc3 = fmaf(wA[3][c*4+0], h4.x, acc3); acc3 = fmaf(wA[3][c*4+1], h4.y, acc3);
                acc3 = fmaf(wA[3][c*4+2], h4.z, acc3); acc3 = fmaf(wA[3][c*4+3], h4.w, acc3);
            }
            {
                float sx[8] = { vx0.x, vx0.y, vx0.z, vx0.w, vx1.x, vx1.y, vx1.z, vx1.w };
#pragma unroll
                for (int j = 0; j < 8; ++j) {
                    acc0 = fmaf(wB[0][j], sx[j], acc0);
                    acc1 = fmaf(wB[1][j], sx[j], acc1);
                    acc2 = fmaf(wB[2][j], sx[j], acc2);
                    acc3 = fmaf(wB[3][j], sx[j], acc3);
                }
            }
            {   // prefetch next x row
                const int tn = (n + 1 < T_STEPS) ? (n + 1) : (T_STEPS - 1);
                vx0 = *(const float4*)(x + (size_t)tn * 128 + ct * 8);
                vx1 = *(const float4*)(x + (size_t)tn * 128 + ct * 8 + 4);
            }
#pragma unroll
            for (int m = 8; m >= 1; m >>= 1) {
                acc0 += __shfl_xor(acc0, m, 64);
                acc1 += __shfl_xor(acc1, m, 64);
                acc2 += __shfl_xor(acc2, m, 64);
                acc3 += __shfl_xor(acc3, m, 64);
            }
            const float ii = sigm(acc0 + bia[0]);
            const float ff = sigm(acc1 + bia[1]);
            const float g2 = tanh_fast(acc2 + bia[2]);
            const float oo = sigm(acc3 + bia[3]);
            cst = ff * cst + ii * g2;
            const float h = oo * tanh_fast(cst);

            if (ct == 0) {
                const unsigned long long pair =
                    ((unsigned long long)(unsigned)(n + 1) << 32) |
                    (unsigned long long)__float_as_uint(h);
                const size_t off = (size_t)(n & (RD - 1)) * 512 + hb + rt;
                st_u64_sc0(&h1f[off], pair);
                st_u64_sc1(&h1s[off], pair);
            }
        }
    } else {
        // ================= LAYER 2: 16 h-indices per WG ====================
        const int rt  = tid >> 5;         // 0..15
        const int ct  = tid & 31;         // 0..31 (16 prim + 4 sec cols)
        const int hb2 = (role - L1WG) * 16;

        float wA[4][16], wB[4][4], bia[4];
#pragma unroll
        for (int q = 0; q < 4; ++q) {
            const int grow = q * 128 + hb2 + rt;
            const float4* pa = (const float4*)(Wih2 + (size_t)grow * 512 + ct * 16);
#pragma unroll
            for (int c = 0; c < 4; ++c) {
                float4 f = pa[c];
                wA[q][c * 4 + 0] = f.x; wA[q][c * 4 + 1] = f.y;
                wA[q][c * 4 + 2] = f.z; wA[q][c * 4 + 3] = f.w;
            }
            float4 b0 = *(const float4*)(Whh2 + (size_t)grow * 128 + ct * 4);
            wB[q][0] = b0.x; wB[q][1] = b0.y; wB[q][2] = b0.z; wB[q][3] = b0.w;
            bia[q] = bih2[grow] + bhh2[grow];
        }

        float cst = 0.0f;
        __syncthreads();   // s_ab visible

        for (int n = 1; n <= T_STEPS; ++n) {
            const int tau = n - 1;
            if (wave == 3 && n >= 8 && (n & 3) == 0 && lane < NWG) {
                const int thr = n - 3;
                unsigned sp = 0;
                for (;;) {
                    int ok = ((int)ld_u32_sc1(&tags[lane]) >= thr);
                    if (__all(ok)) break;
                    if ((++sp & 255u) == 0u) {
                        if (ld_u32_sc1(abf) != 0u) { s_ab[0] = 1u; break; }
                        if (sp >= (1u << 21)) { st_u32_sc1(abf, 1u); s_ab[0] = 1u; break; }
                    }
                }
            }
            // ---- waves 0/1: poll+merge+stage h1[tau] (tag == n) ----------
            if (wave < 2) {
                const size_t off = (size_t)(tau & (RD - 1)) * 512 + wave * 256 + lane * 4;
                const unsigned long long* pf = h1f + off;
                const unsigned long long* ps = h1s + off;
                const unsigned e = (unsigned)n;
                uint4v A, B;
                unsigned sp = 0;
                for (;;) {
                    ld2x16_sc0(pf, A, B);
                    int ok = (A.y == e) & (A.w == e) & (B.y == e) & (B.w == e);
                    if (__all(ok)) break;
                    if ((++sp & 7u) == 0u) {
                        uint4v C, D;
                        ld2x16_sc1(ps, C, D);
                        if (A.y != e) { A.x = C.x; A.y = C.y; }
                        if (A.w != e) { A.z = C.z; A.w = C.w; }
                        if (B.y != e) { B.x = D.x; B.y = D.y; }
                        if (B.w != e) { B.z = D.z; B.w = D.w; }
                        ok = (A.y == e) & (A.w == e) & (B.y == e) & (B.w == e);
                        if (__all(ok)) break;
                        if ((sp & 2047u) == 0u) {
                            if (ld_u32_sc1(abf) != 0u) { s_ab[0] = 1u; break; }
                            if (sp >= (1u << 22)) { st_u32_sc1(abf, 1u); s_ab[0] = 1u; break; }
                        }
                    }
                }
                const int g = wave * 256 + lane * 4;
                float4 vals = make_float4(__uint_as_float(A.x), __uint_as_float(A.z),
                                          __uint_as_float(B.x), __uint_as_float(B.z));
                *(float4*)&h1buf[n & 1][(g >> 5) * 36 + (g & 31)] = vals;
            }
            // ---- wave 2: poll+merge+stage h2[tau-1] (tag == tau) ---------
            if (wave == 2) {
                const size_t off = (size_t)((tau - 1) & (RD - 1)) * 128 + lane * 2;
                const unsigned long long* pf = h2f + off;
                const unsigned long long* ps = h2s + off;
                const unsigned e = (unsigned)tau;
                uint4v A;
                unsigned sp = 0;
                for (;;) {
                    ld1x16_sc0(pf, A);
                    int ok = (A.y == e) & (A.w == e);
                    if (__all(ok)) break;
                    if ((++sp & 7u) == 0u) {
                        uint4v C;
                        ld1x16_sc1(ps, C);
                        if (A.y != e) { A.x = C.x; A.y = C.y; }
                        if (A.w != e) { A.z = C.z; A.w = C.w; }
                        ok = (A.y == e) & (A.w == e);
                        if (__all(ok)) break;
                        if ((sp & 2047u) == 0u) {
                            if (ld_u32_sc1(abf) != 0u) { s_ab[0] = 1u; break; }
                            if (sp >= (1u << 22)) { st_u32_sc1(abf, 1u); s_ab[0] = 1u; break; }
                        }
                    }
                }
                const int pi = lane * 2;
                float2 v2 = make_float2(__uint_as_float(A.x), __uint_as_float(A.z));
                *(float2*)&h2buf[n & 1][(pi >> 4) * 20 + (pi & 15)] = v2;
            }

            __syncthreads();
            if (s_ab[0]) break;
            if (tid == 0) st_u32_sc1(&tags[role], (unsigned)(n + 1));

            // ---- compute: 4 gates x (16 prim + 4 sec) --------------------
            float acc0 = 0.f, acc1 = 0.f, acc2 = 0.f, acc3 = 0.f;
            const float* hv = &h1buf[n & 1][(ct >> 1) * 36 + (ct & 1) * 16];
#pragma unroll
            for (int c = 0; c < 4; ++c) {
                float4 h4 = *(const float4*)(hv + c * 4);
                acc0 = fmaf(wA[0][c*4+0], h4.x, acc0); acc0 = fmaf(wA[0][c*4+1], h4.y, acc0);
                acc0 = fmaf(wA[0][c*4+2], h4.z, acc0); acc0 = fmaf(wA[0][c*4+3], h4.w, acc0);
                acc1 = fmaf(wA[1][c*4+0], h4.x, acc1); acc1 = fmaf(wA[1][c*4+1], h4.y, acc1);
                acc1 = fmaf(wA[1][c*4+2], h4.z, acc1); acc1 = fmaf(wA[1][c*4+3], h4.w, acc1);
                acc2 = fmaf(wA[2][c*4+0], h4.x, acc2); acc2 = fmaf(wA[2][c*4+1], h4.y, acc2);
                acc2 = fmaf(wA[2][c*4+2], h4.z, acc2); acc2 = fmaf(wA[2][c*4+3], h4.w, acc2);
                acc3 = fmaf(wA[3][c*4+0], h4.x, acc3); acc3 = fmaf(wA[3][c*4+1], h4.y, acc3);
                acc3 = fmaf(wA[3][c*4+2], h4.z, acc3); acc3 = fmaf(wA[3][c*4+3], h4.w, acc3);
            }
            {
                float4 s4 = *(const float4*)&h2buf[n & 1][(ct >> 2) * 20 + (ct & 3) * 4];
                const float sv[4] = { s4.x, s4.y, s4.z, s4.w };
#pragma unroll
                for (int j = 0; j < 4; ++j) {
                    acc0 = fmaf(wB[0][j], sv[j], acc0);
                    acc1 = fmaf(wB[1][j], sv[j], acc1);
                    acc2 = fmaf(wB[2][j], sv[j], acc2);
                    acc3 = fmaf(wB[3][j], sv[j], acc3);
                }
            }
#pragma unroll
            for (int m = 16; m >= 1; m >>= 1) {
                acc0 += __shfl_xor(acc0, m, 64);
                acc1 += __shfl_xor(acc1, m, 64);
                acc2 += __shfl_xor(acc2, m, 64);
                acc3 += __shfl_xor(acc3, m, 64);
            }
            const float ii = sigm(acc0 + bia[0]);
            const float ff = sigm(acc1 + bia[1]);
            const float g2 = tanh_fast(acc2 + bia[2]);
            const float oo = sigm(acc3 + bia[3]);
            cst = ff * cst + ii * g2;
            const float h = oo * tanh_fast(cst);

            if (ct == 0) {
                const unsigned long long pair =
                    ((unsigned long long)(unsigned)n << 32) |
                    (unsigned long long)__float_as_uint(h);
                const size_t off = (size_t)(tau & (RD - 1)) * 128 + hb2 + rt;
                st_u64_sc0(&h2f[off], pair);
                st_u64_sc1(&h2s[off], pair);
                out[(size_t)tau * 128 + hb2 + rt] = h;
            }
        }
    }
}

extern "C" void kernel_launch(void* const* d_in, const int* in_sizes, int n_in,
                              void* d_out, int out_size, void* d_ws, size_t ws_size,
                              hipStream_t stream)
{
    const float* x    = (const float*)d_in[0];
    const float* Wih1 = (const float*)d_in[1];
    const float* Whh1 = (const float*)d_in[2];
    const float* bih1 = (const float*)d_in[3];
    const float* bhh1 = (const float*)d_in[4];
    const float* Wih2 = (const float*)d_in[5];
    const float* Whh2 = (const float*)d_in[6];
    const float* bih2 = (const float*)d_in[7];
    const float* bhh2 = (const float*)d_in[8];
    unsigned int* ws  = (unsigned int*)d_ws;

    hipLaunchKernelGGL(lstm_init, dim3(96), dim3(256), 0, stream, ws);
    hipLaunchKernelGGL(lstm_persist, dim3(GRID), dim3(BLK), 0, stream,
                       x, Wih1, Whh1, bih1, bhh1, Wih2, Whh2, bih2, bhh2,
                       (float*)d_out, ws);
}